// Round 1
// baseline (506.520 us; speedup 1.0000x reference)
//
#include <hip/hip_runtime.h>
#include <math.h>

// x: (8,64,384,384) fp32; params: (8,2) fp32.
#define B_  8
#define C_  64
#define H_  384
#define W_  384

#define TX   128             // output tile width
#define TY   64              // output tile height
#define HALO 4               // covers taps for all k in {5..9} incl. even-k resize blend
#define SH   (TY + 2*HALO)   // 72 rows of horizontal-pass output staged in LDS
#define TXP  132             // padded LDS stride for sTmp (16B-aligned, bank-spread)

#define NTX     (W_ / TX)        // 3
#define NTY     (H_ / TY)        // 6
#define NTILES  (NTX * NTY)      // 18
#define NBLK    (NTILES * C_ * B_)  // 9216  (divisible by 8 -> bijective XCD swizzle)

// Horizontal pass reads global directly (no sIn stage): 16-float windows overlap
// between neighboring 8-col groups, but overlaps are same-wave L1/L2 hits, not HBM.
// Only the horizontal-pass RESULT (sTmp) goes to LDS; vertical pass consumes it.
// HBM read amplification drops from (72x40)/(64x32)=1.41x to (TY+8)/TY=1.125x.

template<int K>
__device__ __forceinline__ void process_tile(
    float (*sTmp)[TXP],
    const float* __restrict__ xp, float* __restrict__ op,
    int tx0, int ty0, float sigma, int tid)
{
    constexpr int  PAD  = K / 2;
    constexpr bool EVEN = ((K & 1) == 0);

    // normalized 1D Gaussian weights, fully in registers
    float g[K];
    {
        const float inv2s2 = 1.0f / (2.0f * sigma * sigma);
        float S = 0.0f;
        #pragma unroll
        for (int i = 0; i < K; ++i) {
            float d = (float)(i - PAD);
            g[i] = expf(-d * d * inv2s2);
            S += g[i];
        }
        const float invS = 1.0f / S;
        #pragma unroll
        for (int i = 0; i < K; ++i) g[i] *= invS;
    }

    // ---- horizontal pass: each task = (row r, 8-col group g8), global -> LDS ----
    // 72 rows x 16 groups = 1152 tasks
    for (int li = tid; li < SH * (TX / 8); li += 512) {
        const int r  = li >> 4;
        const int g8 = (li & 15) * 8;
        const int gr = ty0 - HALO + r;

        float V[16];
        if (gr >= 0 && gr < H_) {
            // base col = tx0 - 4 + g8  ->  (mult of 8) - 4  ->  16B-aligned
            const float* rp = xp + (size_t)gr * W_ + (tx0 - HALO + g8);
            #pragma unroll
            for (int i = 0; i < 4; ++i) {
                const int gc = tx0 - HALO + g8 + 4 * i;   // each float4 fully in- or out-of-bounds
                float4 v = make_float4(0.f, 0.f, 0.f, 0.f);
                if (gc >= 0 && gc < W_)
                    v = *reinterpret_cast<const float4*>(rp + 4 * i);
                V[4*i+0] = v.x; V[4*i+1] = v.y; V[4*i+2] = v.z; V[4*i+3] = v.w;
            }
        } else {
            #pragma unroll
            for (int i = 0; i < 16; ++i) V[i] = 0.f;
        }

        float vals[8];
        #pragma unroll
        for (int j = 0; j < 8; ++j) {
            float a0 = 0.0f;
            #pragma unroll
            for (int t = 0; t < K; ++t) a0 += g[t] * V[j + 4 - PAD + t];
            float val = a0;
            if (EVEN) {
                float a1 = 0.0f;
                #pragma unroll
                for (int t = 0; t < K; ++t) a1 += g[t] * V[j + 5 - PAD + t];
                const float fw = ((float)(tx0 + g8 + j) + 0.5f) * (1.0f / (float)W_);
                val = a0 + fw * (a1 - a0);
            }
            vals[j] = val;
        }
        // vectorized LDS writes (addr = r*132 + g8 -> 16B aligned)
        *reinterpret_cast<float4*>(&sTmp[r][g8])     = make_float4(vals[0], vals[1], vals[2], vals[3]);
        *reinterpret_cast<float4*>(&sTmp[r][g8 + 4]) = make_float4(vals[4], vals[5], vals[6], vals[7]);
    }
    __syncthreads();

    // ---- vertical pass: each task = (4-row group yg, col xx) ----
    // (TY/4)=16 groups x 128 cols = 2048 tasks (exactly 4 iters of 512)
    for (int li = tid; li < (TY / 4) * TX; li += 512) {
        const int yg = li >> 7;
        const int xx = li & (TX - 1);
        float U[12];
        #pragma unroll
        for (int i = 0; i < 12; ++i) U[i] = sTmp[yg * 4 + i][xx];   // stride-1 across lanes: conflict-free
        #pragma unroll
        for (int j = 0; j < 4; ++j) {
            float a0 = 0.0f;
            #pragma unroll
            for (int t = 0; t < K; ++t) a0 += g[t] * U[j + 4 - PAD + t];
            float val = a0;
            if (EVEN) {
                float a1 = 0.0f;
                #pragma unroll
                for (int t = 0; t < K; ++t) a1 += g[t] * U[j + 5 - PAD + t];
                const float fh = ((float)(ty0 + yg * 4 + j) + 0.5f) * (1.0f / (float)H_);
                val = a0 + fh * (a1 - a0);
            }
            op[(size_t)(ty0 + yg * 4 + j) * W_ + (tx0 + xx)] = val;
        }
    }
}

__global__ __launch_bounds__(512) void gauss_blur_kernel(
    const float* __restrict__ x, const float* __restrict__ params,
    float* __restrict__ out)
{
    // XCD-contiguous bijective swizzle: blocks with the same (bid & 7) land on the
    // same XCD (round-robin dispatch); give each XCD a contiguous chunk of the
    // (b, c, tile) work space so vertical-halo re-reads hit that XCD's L2.
    const int bid  = blockIdx.x;               // 0..9215
    const int gidx = (bid & 7) * (NBLK / 8) + (bid >> 3);

    const int tile = gidx % NTILES;            // tiles innermost: neighbors same XCD
    const int bc   = gidx / NTILES;
    const int c    = bc & (C_ - 1);
    const int b    = bc >> 6;

    const int tx0 = (tile % NTX) * TX;
    const int ty0 = (tile / NTX) * TY;

    // per-batch params (redundant per thread; trivial)
    const float p0 = params[2 * b + 0];
    const float p1 = params[2 * b + 1];
    const float k_int = truncf(p0);                       // torch .long() truncation
    const float s0 = 1.0f / (1.0f + expf(-k_int));
    int k = (int)floorf(5.0f + 5.0f * s0);                // {5..9}
    if (k < 5) k = 5;
    if (k > 9) k = 9;
    const float sigma = 0.5f + 4.5f * (1.0f / (1.0f + expf(-p1)));

    __shared__ float sTmp[SH][TXP];            // 72*132*4 = 38,016 B

    const size_t plane = (size_t)(b * C_ + c) * (size_t)(H_ * W_);
    const float* xp = x + plane;
    float*       op = out + plane;
    const int tid = threadIdx.x;

    switch (k) {   // block-uniform (k depends only on b)
        case 5:  process_tile<5>(sTmp, xp, op, tx0, ty0, sigma, tid); break;
        case 6:  process_tile<6>(sTmp, xp, op, tx0, ty0, sigma, tid); break;
        case 7:  process_tile<7>(sTmp, xp, op, tx0, ty0, sigma, tid); break;
        case 8:  process_tile<8>(sTmp, xp, op, tx0, ty0, sigma, tid); break;
        default: process_tile<9>(sTmp, xp, op, tx0, ty0, sigma, tid); break;
    }
}

extern "C" void kernel_launch(void* const* d_in, const int* in_sizes, int n_in,
                              void* d_out, int out_size, void* d_ws, size_t ws_size,
                              hipStream_t stream) {
    const float* x      = (const float*)d_in[0];
    const float* params = (const float*)d_in[1];
    float* out          = (float*)d_out;

    dim3 grid(NBLK, 1, 1);    // 9216 blocks, XCD-swizzled in-kernel
    dim3 block(512, 1, 1);
    gauss_blur_kernel<<<grid, block, 0, stream>>>(x, params, out);
}

// Round 2
// 494.979 us; speedup vs baseline: 1.0233x; 1.0233x over previous
//
#include <hip/hip_runtime.h>
#include <math.h>

// x: (8,64,384,384) fp32; params: (8,2) fp32.
#define B_  8
#define C_  64
#define H_  384
#define W_  384

#define TX   64              // output tile width
#define TY   32              // output tile height
#define HALO 4               // covers taps for all k in {5..9} incl. even-k resize blend
#define SW   (TX + 2*HALO)   // 72 staged cols (data)
#define SH   (TY + 2*HALO)   // 40 staged rows
#define SWP  76              // padded LDS stride for sIn  (16B-aligned, bank-spread)
#define TXP  68              // padded LDS stride for sTmp (16B-aligned, bank-spread)

#define NTX     (W_ / TX)            // 6
#define NTY     (H_ / TY)            // 12
#define NTILES  (NTX * NTY)          // 72
#define NBLK    (NTILES * C_ * B_)   // 36864  (divisible by 8 -> bijective XCD swizzle)

template<int K>
__device__ __forceinline__ void process_tile(
    float (*sIn)[SWP], float (*sTmp)[TXP],
    float* __restrict__ op, int tx0, int ty0, float sigma, int tid)
{
    constexpr int  PAD  = K / 2;
    constexpr bool EVEN = ((K & 1) == 0);

    // normalized 1D Gaussian weights, fully in registers
    float g[K];
    {
        const float inv2s2 = 1.0f / (2.0f * sigma * sigma);
        float S = 0.0f;
        #pragma unroll
        for (int i = 0; i < K; ++i) {
            float d = (float)(i - PAD);
            g[i] = expf(-d * d * inv2s2);
            S += g[i];
        }
        const float invS = 1.0f / S;
        #pragma unroll
        for (int i = 0; i < K; ++i) g[i] *= invS;
    }

    // ---- horizontal pass: each task = (row r, 8-col group gx) ----
    // 40 rows x 8 groups = 320 tasks
    for (int li = tid; li < SH * 8; li += 256) {
        const int r  = li >> 3;
        const int g8 = (li & 7) * 8;
        float V[16];
        #pragma unroll
        for (int i = 0; i < 16; ++i) V[i] = sIn[r][g8 + i];   // 32B-aligned -> b128s
        #pragma unroll
        for (int j = 0; j < 8; ++j) {
            float a0 = 0.0f;
            #pragma unroll
            for (int t = 0; t < K; ++t) a0 += g[t] * V[j + 4 - PAD + t];
            float val = a0;
            if (EVEN) {
                float a1 = 0.0f;
                #pragma unroll
                for (int t = 0; t < K; ++t) a1 += g[t] * V[j + 5 - PAD + t];
                const float fw = ((float)(tx0 + g8 + j) + 0.5f) * (1.0f / (float)W_);
                val = a0 + fw * (a1 - a0);
            }
            sTmp[r][g8 + j] = val;
        }
    }
    __syncthreads();

    // ---- vertical pass: each task = (4-row group yg, col xx) ----
    // (TY/4)=8 groups x 64 cols = 512 tasks
    for (int li = tid; li < (TY / 4) * 64; li += 256) {
        const int yg = li >> 6;
        const int xx = li & 63;
        float U[12];
        #pragma unroll
        for (int i = 0; i < 12; ++i) U[i] = sTmp[yg * 4 + i][xx];
        #pragma unroll
        for (int j = 0; j < 4; ++j) {
            float a0 = 0.0f;
            #pragma unroll
            for (int t = 0; t < K; ++t) a0 += g[t] * U[j + 4 - PAD + t];
            float val = a0;
            if (EVEN) {
                float a1 = 0.0f;
                #pragma unroll
                for (int t = 0; t < K; ++t) a1 += g[t] * U[j + 5 - PAD + t];
                const float fh = ((float)(ty0 + yg * 4 + j) + 0.5f) * (1.0f / (float)H_);
                val = a0 + fh * (a1 - a0);
            }
            // output is never re-read: nontemporal store keeps the write stream
            // from evicting the halo lines we want to stay resident in L2
            __builtin_nontemporal_store(val, &op[(size_t)(ty0 + yg * 4 + j) * W_ + (tx0 + xx)]);
        }
    }
}

__global__ __launch_bounds__(256) void gauss_blur_kernel(
    const float* __restrict__ x, const float* __restrict__ params,
    float* __restrict__ out)
{
    // Bijective XCD swizzle: hardware round-robins consecutive blockIdx.x across
    // the 8 XCDs, so (bid & 7) == XCD id. Give each XCD one contiguous chunk of
    // the (b, c, tile) work space with TILES INNERMOST: all 72 tiles of a plane
    // (576 KB << 4 MB L2) run consecutively on one XCD, so the 1.41x halo
    // re-reads (+1 horiz, +6 vert neighbors) hit that XCD's L2 instead of HBM.
    const int bid  = blockIdx.x;                     // 0..36863
    const int gidx = (bid & 7) * (NBLK / 8) + (bid >> 3);

    const int tile = gidx % NTILES;
    const int bc   = gidx / NTILES;
    const int c    = bc & (C_ - 1);
    const int b    = bc >> 6;

    const int tx0  = (tile % NTX) * TX;
    const int ty0  = (tile / NTX) * TY;

    // per-batch params (redundant per thread; trivial)
    const float p0 = params[2 * b + 0];
    const float p1 = params[2 * b + 1];
    const float k_int = truncf(p0);                       // torch .long() truncation
    const float s0 = 1.0f / (1.0f + expf(-k_int));
    int k = (int)floorf(5.0f + 5.0f * s0);                // {5..9}
    if (k < 5) k = 5;
    if (k > 9) k = 9;
    const float sigma = 0.5f + 4.5f * (1.0f / (1.0f + expf(-p1)));

    __shared__ float sIn[SH][SWP];
    __shared__ float sTmp[SH][TXP];

    const size_t plane = (size_t)(b * C_ + c) * (size_t)(H_ * W_);
    const float* xp = x + plane;
    float*       op = out + plane;
    const int tid = threadIdx.x;

    // ---- stage input tile as float4 (whole float4 is in- or out-of-bounds) ----
    // 40 rows x 18 float4 = 720 tasks
    for (int li = tid; li < SH * (SW / 4); li += 256) {
        const int r  = li / (SW / 4);
        const int c4 = li - r * (SW / 4);
        const int gr = ty0 - HALO + r;
        const int gc = tx0 - HALO + c4 * 4;
        float4 v = make_float4(0.f, 0.f, 0.f, 0.f);
        if (gr >= 0 && gr < H_ && gc >= 0 && gc < W_)
            v = *reinterpret_cast<const float4*>(xp + (size_t)gr * W_ + gc);
        *reinterpret_cast<float4*>(&sIn[r][c4 * 4]) = v;
    }
    __syncthreads();

    switch (k) {   // wave-uniform (k depends only on b)
        case 5:  process_tile<5>(sIn, sTmp, op, tx0, ty0, sigma, tid); break;
        case 6:  process_tile<6>(sIn, sTmp, op, tx0, ty0, sigma, tid); break;
        case 7:  process_tile<7>(sIn, sTmp, op, tx0, ty0, sigma, tid); break;
        case 8:  process_tile<8>(sIn, sTmp, op, tx0, ty0, sigma, tid); break;
        default: process_tile<9>(sIn, sTmp, op, tx0, ty0, sigma, tid); break;
    }
}

extern "C" void kernel_launch(void* const* d_in, const int* in_sizes, int n_in,
                              void* d_out, int out_size, void* d_ws, size_t ws_size,
                              hipStream_t stream) {
    const float* x      = (const float*)d_in[0];
    const float* params = (const float*)d_in[1];
    float* out          = (float*)d_out;

    dim3 grid(NBLK, 1, 1);    // 36864 blocks, XCD-swizzled in-kernel
    dim3 block(256, 1, 1);
    gauss_blur_kernel<<<grid, block, 0, stream>>>(x, params, out);
}

// Round 3
// 491.214 us; speedup vs baseline: 1.0312x; 1.0077x over previous
//
#include <hip/hip_runtime.h>
#include <math.h>

// x: (8,64,384,384) fp32; params: (8,2) fp32.
#define B_  8
#define C_  64
#define H_  384
#define W_  384

#define TX   64              // output tile width
#define TY   32              // output tile height
#define HALO 4               // covers taps for all k in {5..9} incl. even-k resize blend
#define SW   (TX + 2*HALO)   // 72 staged cols (data)
#define SH   (TY + 2*HALO)   // 40 staged rows
#define SWP  76              // padded LDS stride for sIn  (16B-aligned, bank-spread)
#define TXP  68              // padded LDS stride for sTmp (16B-aligned, bank-spread)

#define NTX     (W_ / TX)            // 6
#define NTY     (H_ / TY)            // 12
#define NTILES  (NTX * NTY)          // 72
#define NBLK    (NTILES * C_ * B_)   // 36864  (divisible by 8 -> bijective XCD swizzle)

typedef float f2v __attribute__((ext_vector_type(2)));

template<int K>
__device__ __forceinline__ void process_tile(
    float (*sIn)[SWP], float (*sTmp)[TXP],
    float* __restrict__ op, int tx0, int ty0, float sigma, int tid)
{
    constexpr int  PAD  = K / 2;
    constexpr bool EVEN = ((K & 1) == 0);

    // normalized 1D Gaussian weights, fully in registers
    float g[K];
    {
        const float inv2s2 = 1.0f / (2.0f * sigma * sigma);
        float S = 0.0f;
        #pragma unroll
        for (int i = 0; i < K; ++i) {
            float d = (float)(i - PAD);
            g[i] = expf(-d * d * inv2s2);
            S += g[i];
        }
        const float invS = 1.0f / S;
        #pragma unroll
        for (int i = 0; i < K; ++i) g[i] *= invS;
    }

    // ---- horizontal pass: each task = (row r, 8-col group gx) ----
    // 40 rows x 8 groups = 320 tasks; reads 4x ds_read_b128, writes 2x ds_write_b128
    for (int li = tid; li < SH * 8; li += 256) {
        const int r  = li >> 3;
        const int g8 = (li & 7) * 8;
        float V[16];
        #pragma unroll
        for (int i = 0; i < 16; ++i) V[i] = sIn[r][g8 + i];   // 32B-aligned -> b128s
        float vals[8];
        #pragma unroll
        for (int j = 0; j < 8; ++j) {
            float a0 = 0.0f;
            #pragma unroll
            for (int t = 0; t < K; ++t) a0 += g[t] * V[j + 4 - PAD + t];
            float val = a0;
            if (EVEN) {
                float a1 = 0.0f;
                #pragma unroll
                for (int t = 0; t < K; ++t) a1 += g[t] * V[j + 5 - PAD + t];
                const float fw = ((float)(tx0 + g8 + j) + 0.5f) * (1.0f / (float)W_);
                val = a0 + fw * (a1 - a0);
            }
            vals[j] = val;
        }
        // r*68 + g8 is 16B-aligned (68*4 = 272 = 17*16); bank-uniform across the wave
        *reinterpret_cast<float4*>(&sTmp[r][g8])     = make_float4(vals[0], vals[1], vals[2], vals[3]);
        *reinterpret_cast<float4*>(&sTmp[r][g8 + 4]) = make_float4(vals[4], vals[5], vals[6], vals[7]);
    }
    __syncthreads();

    // ---- vertical pass: each task = 2 cols x 4 rows; 8 row-groups x 32 col-pairs
    //      = 256 tasks (exactly one per thread). 12x ds_read_b64 instead of the
    //      old 12x ds_read_b32 per column: 12 B/px at b64/b128 LDS rate (~85 B/cyc)
    //      instead of b32 rate (~44 B/cyc). Bank-uniform (4 lanes/bank = floor).
    {
        const int yg = tid >> 5;             // 0..7  (4-row output group)
        const int x2 = (tid & 31) * 2;       // 0,2,...,62
        f2v U[12];
        #pragma unroll
        for (int i = 0; i < 12; ++i)
            U[i] = *reinterpret_cast<const f2v*>(&sTmp[yg * 4 + i][x2]);   // 8B-aligned
        #pragma unroll
        for (int j = 0; j < 4; ++j) {
            f2v a0 = {0.0f, 0.0f};
            #pragma unroll
            for (int t = 0; t < K; ++t) a0 += g[t] * U[j + 4 - PAD + t];
            f2v val = a0;
            if (EVEN) {
                f2v a1 = {0.0f, 0.0f};
                #pragma unroll
                for (int t = 0; t < K; ++t) a1 += g[t] * U[j + 5 - PAD + t];
                const float fh = ((float)(ty0 + yg * 4 + j) + 0.5f) * (1.0f / (float)H_);
                val = a0 + fh * (a1 - a0);
            }
            // output is never re-read: nontemporal float2 store
            __builtin_nontemporal_store(val,
                reinterpret_cast<f2v*>(&op[(size_t)(ty0 + yg * 4 + j) * W_ + (tx0 + x2)]));
        }
    }
}

__global__ __launch_bounds__(256) void gauss_blur_kernel(
    const float* __restrict__ x, const float* __restrict__ params,
    float* __restrict__ out)
{
    // Bijective XCD swizzle (kept: mechanism sound for L2 locality, cost zero).
    const int bid  = blockIdx.x;                     // 0..36863
    const int gidx = (bid & 7) * (NBLK / 8) + (bid >> 3);

    const int tile = gidx % NTILES;
    const int bc   = gidx / NTILES;
    const int c    = bc & (C_ - 1);
    const int b    = bc >> 6;

    const int tx0  = (tile % NTX) * TX;
    const int ty0  = (tile / NTX) * TY;

    // per-batch params (redundant per thread; trivial)
    const float p0 = params[2 * b + 0];
    const float p1 = params[2 * b + 1];
    const float k_int = truncf(p0);                       // torch .long() truncation
    const float s0 = 1.0f / (1.0f + expf(-k_int));
    int k = (int)floorf(5.0f + 5.0f * s0);                // {5..9}
    if (k < 5) k = 5;
    if (k > 9) k = 9;
    const float sigma = 0.5f + 4.5f * (1.0f / (1.0f + expf(-p1)));

    __shared__ float sIn[SH][SWP];
    __shared__ float sTmp[SH][TXP];

    const size_t plane = (size_t)(b * C_ + c) * (size_t)(H_ * W_);
    const float* xp = x + plane;
    float*       op = out + plane;
    const int tid = threadIdx.x;

    // ---- stage input tile as float4 (whole float4 is in- or out-of-bounds) ----
    // 40 rows x 18 float4 = 720 tasks
    for (int li = tid; li < SH * (SW / 4); li += 256) {
        const int r  = li / (SW / 4);
        const int c4 = li - r * (SW / 4);
        const int gr = ty0 - HALO + r;
        const int gc = tx0 - HALO + c4 * 4;
        float4 v = make_float4(0.f, 0.f, 0.f, 0.f);
        if (gr >= 0 && gr < H_ && gc >= 0 && gc < W_)
            v = *reinterpret_cast<const float4*>(xp + (size_t)gr * W_ + gc);
        *reinterpret_cast<float4*>(&sIn[r][c4 * 4]) = v;
    }
    __syncthreads();

    switch (k) {   // wave-uniform (k depends only on b)
        case 5:  process_tile<5>(sIn, sTmp, op, tx0, ty0, sigma, tid); break;
        case 6:  process_tile<6>(sIn, sTmp, op, tx0, ty0, sigma, tid); break;
        case 7:  process_tile<7>(sIn, sTmp, op, tx0, ty0, sigma, tid); break;
        case 8:  process_tile<8>(sIn, sTmp, op, tx0, ty0, sigma, tid); break;
        default: process_tile<9>(sIn, sTmp, op, tx0, ty0, sigma, tid); break;
    }
}

extern "C" void kernel_launch(void* const* d_in, const int* in_sizes, int n_in,
                              void* d_out, int out_size, void* d_ws, size_t ws_size,
                              hipStream_t stream) {
    const float* x      = (const float*)d_in[0];
    const float* params = (const float*)d_in[1];
    float* out          = (float*)d_out;

    dim3 grid(NBLK, 1, 1);    // 36864 blocks, XCD-swizzled in-kernel
    dim3 block(256, 1, 1);
    gauss_blur_kernel<<<grid, block, 0, stream>>>(x, params, out);
}